// Round 9
// baseline (275.591 us; speedup 1.0000x reference)
//
#include <hip/hip_runtime.h>

// 3-layer GAT (PyG GATConv) on MI355X.
// CSR build: count_rank fused with layer-1 GEMM (heterogeneous blocks;
// returning atomics are a ~25G ops/s device ceiling — gemm1 rides free)
// -> scan -> fill (pure scatter, no atomics).
// Layers are collapsed into 3 mega-kernels:
//   aggr1+gemm2 (softmax-gather over bf16 H1; epilogue computes H2 = relu(out)@W2
//                in LDS/registers, emitting bf16 H2 + layer-2 attention dots),
//   aggr2+gemm3 (same pattern),
//   aggr3+mean  (grid-stride, no B3 materialization, LDS-reduced atomics).
// Eliminates all f32 B round trips (~76 MB) and 4 launches.

constexpr int BLOCK = 256;
constexpr int CPAD = 32;      // counter stride in ints (128 B) to spread atomic lines
constexpr int NCOUNT = 1024;  // count blocks in the fused kernel

__device__ __forceinline__ float llrelu(float x) { return x >= 0.f ? x : 0.2f * x; }

__device__ __forceinline__ unsigned short f2bf(float f) {
    unsigned int u = __float_as_uint(f);
    u += 0x7FFFu + ((u >> 16) & 1u);  // round-to-nearest-even
    return (unsigned short)(u >> 16);
}
__device__ __forceinline__ float bf2f(unsigned short h) {
    return __uint_as_float((unsigned int)h << 16);
}

__global__ void zero_strided_kernel(int* __restrict__ p, int count) {
    int i = blockIdx.x * blockDim.x + threadIdx.x;
    int stride = gridDim.x * blockDim.x;
    for (; i < count; i += stride) p[(size_t)i * CPAD] = 0;
}

__global__ void scan_phase1(const int* __restrict__ counts, int n,
                            int* __restrict__ excl, int* __restrict__ block_sums) {
    __shared__ int s[1024];
    int tid = threadIdx.x;
    int gid = blockIdx.x * 1024 + tid;
    int v = (gid < n) ? counts[(size_t)gid * CPAD] : 0;
    s[tid] = v;
    for (int off = 1; off < 1024; off <<= 1) {
        __syncthreads();
        int t = (tid >= off) ? s[tid - off] : 0;
        __syncthreads();
        s[tid] += t;
    }
    __syncthreads();
    if (gid < n) excl[gid] = s[tid] - v;
    if (tid == 1023) block_sums[blockIdx.x] = s[tid];
}

__global__ void scan_phase2(int* __restrict__ block_sums, int nb) {
    __shared__ int s[1024];
    int tid = threadIdx.x;
    int v = (tid < nb) ? block_sums[tid] : 0;
    s[tid] = v;
    for (int off = 1; off < 1024; off <<= 1) {
        __syncthreads();
        int t = (tid >= off) ? s[tid - off] : 0;
        __syncthreads();
        s[tid] += t;
    }
    __syncthreads();
    if (tid < nb) block_sums[tid] = s[tid] - v;  // exclusive
}

__global__ void scan_phase3(int* __restrict__ row_start, const int* __restrict__ block_sums,
                            int n, int E) {
    int gid = blockIdx.x * blockDim.x + threadIdx.x;
    if (gid < n) row_start[gid] += block_sums[gid >> 10];
    if (gid == 0) row_start[n] = E;
}

// Pure scatter: slot = row_start[dst] + rank. 4-deep software pipeline.
__global__ void fill_kernel(const int* __restrict__ src, const int* __restrict__ dst,
                            const int* __restrict__ rank, int E,
                            const int* __restrict__ row_start, int* __restrict__ esrc) {
    int tidg = blockIdx.x * blockDim.x + threadIdx.x;
    int nthr = gridDim.x * blockDim.x;
    for (int base = tidg; base < E; base += 4 * nthr) {
        int idx[4], d[4], rk[4], sv[4], rs[4];
        bool ok[4];
#pragma unroll
        for (int u = 0; u < 4; ++u) {
            idx[u] = base + u * nthr;
            ok[u] = idx[u] < E;
            int safe = ok[u] ? idx[u] : 0;
            d[u] = dst[safe];
            rk[u] = rank[safe];
            sv[u] = src[safe];
        }
#pragma unroll
        for (int u = 0; u < 4; ++u) rs[u] = row_start[d[u]];
#pragma unroll
        for (int u = 0; u < 4; ++u)
            if (ok[u]) esrc[rs[u] + rk[u]] = sv[u];
    }
}

// H(bf16) = relu?(X) @ W, plus attention dots Ssrc/Sdst from exact f32 accs.
template <int FIN, int FOUT, bool RELU_IN>
__device__ __forceinline__ void gemm_att_body(
    const float* __restrict__ X, const float* __restrict__ W,
    const float* __restrict__ asrc, const float* __restrict__ adst,
    unsigned short* __restrict__ H, float* __restrict__ Ssrc,
    float* __restrict__ Sdst, int n, int gblk) {
    constexpr int CG = FOUT / 4;
    constexpr int NG = BLOCK / CG;
    constexpr int TN = NG * 4;
    constexpr int S = FIN + 4;
    __shared__ float Xs[TN * S];
    __shared__ float Ws[FIN * FOUT];

    int tid = threadIdx.x;
    int n0_blk = gblk * TN;

    for (int t = tid; t < FIN * FOUT / 4; t += BLOCK) {
        float4 v = ((const float4*)W)[t];
        *(float4*)&Ws[t * 4] = v;
    }
    constexpr int RW = FIN / 4;
    for (int t = tid; t < TN * RW; t += BLOCK) {
        int r = t / RW, c = t % RW;
        int gr = n0_blk + r;
        if (gr >= n) gr = n - 1;
        float4 v = ((const float4*)(X + (size_t)gr * FIN))[c];
        if (RELU_IN) {
            v.x = fmaxf(v.x, 0.f); v.y = fmaxf(v.y, 0.f);
            v.z = fmaxf(v.z, 0.f); v.w = fmaxf(v.w, 0.f);
        }
        *(float4*)&Xs[r * S + c * 4] = v;
    }
    __syncthreads();

    int tx = tid % CG;
    int ty = tid / CG;
    int c0 = tx * 4;
    int nloc = ty * 4;

    float acc[4][4];
#pragma unroll
    for (int i = 0; i < 4; ++i)
#pragma unroll
        for (int j = 0; j < 4; ++j) acc[i][j] = 0.f;

#pragma unroll 2
    for (int kc = 0; kc < FIN / 4; ++kc) {
        float4 xv[4], wv[4];
#pragma unroll
        for (int i = 0; i < 4; ++i) xv[i] = *(const float4*)&Xs[(nloc + i) * S + kc * 4];
#pragma unroll
        for (int kk = 0; kk < 4; ++kk) wv[kk] = *(const float4*)&Ws[(kc * 4 + kk) * FOUT + c0];
#pragma unroll
        for (int i = 0; i < 4; ++i) {
            float xi0 = xv[i].x, xi1 = xv[i].y, xi2 = xv[i].z, xi3 = xv[i].w;
            acc[i][0] = fmaf(xi0, wv[0].x, acc[i][0]);
            acc[i][1] = fmaf(xi0, wv[0].y, acc[i][1]);
            acc[i][2] = fmaf(xi0, wv[0].z, acc[i][2]);
            acc[i][3] = fmaf(xi0, wv[0].w, acc[i][3]);
            acc[i][0] = fmaf(xi1, wv[1].x, acc[i][0]);
            acc[i][1] = fmaf(xi1, wv[1].y, acc[i][1]);
            acc[i][2] = fmaf(xi1, wv[1].z, acc[i][2]);
            acc[i][3] = fmaf(xi1, wv[1].w, acc[i][3]);
            acc[i][0] = fmaf(xi2, wv[2].x, acc[i][0]);
            acc[i][1] = fmaf(xi2, wv[2].y, acc[i][1]);
            acc[i][2] = fmaf(xi2, wv[2].z, acc[i][2]);
            acc[i][3] = fmaf(xi2, wv[2].w, acc[i][3]);
            acc[i][0] = fmaf(xi3, wv[3].x, acc[i][0]);
            acc[i][1] = fmaf(xi3, wv[3].y, acc[i][1]);
            acc[i][2] = fmaf(xi3, wv[3].z, acc[i][2]);
            acc[i][3] = fmaf(xi3, wv[3].w, acc[i][3]);
        }
    }

    float4 as4 = *(const float4*)&asrc[c0];
    float4 ad4 = *(const float4*)&adst[c0];

#pragma unroll
    for (int i = 0; i < 4; ++i) {
        int node = n0_blk + nloc + i;
        bool ok = node < n;
        if (ok) {
            ushort4 hb;
            hb.x = f2bf(acc[i][0]); hb.y = f2bf(acc[i][1]);
            hb.z = f2bf(acc[i][2]); hb.w = f2bf(acc[i][3]);
            *(ushort4*)&H[(size_t)node * FOUT + c0] = hb;
        }
        float vs = acc[i][0] * as4.x + acc[i][1] * as4.y + acc[i][2] * as4.z + acc[i][3] * as4.w;
        float vd = acc[i][0] * ad4.x + acc[i][1] * ad4.y + acc[i][2] * ad4.z + acc[i][3] * ad4.w;
#pragma unroll
        for (int off = CG / 2; off > 0; off >>= 1) {
            vs += __shfl_xor(vs, off, CG);
            vd += __shfl_xor(vd, off, CG);
        }
        if (tx == 0 && ok) {
            Ssrc[node] = vs;
            Sdst[node] = vd;
        }
    }
}

// Fused layer-1 GEMM + count_rank (+ facc zero). Even blocks GEMM, odd count.
template <int FIN, int FOUT>
__global__ void gemm_att_count_kernel(const float* __restrict__ X, const float* __restrict__ W,
                                      const float* __restrict__ asrc, const float* __restrict__ adst,
                                      unsigned short* __restrict__ H, float* __restrict__ Ssrc,
                                      float* __restrict__ Sdst, int n, int ngemm,
                                      const int* __restrict__ dst, int E,
                                      int* __restrict__ counts, int* __restrict__ rank,
                                      float* __restrict__ facc) {
    int bid = blockIdx.x;
    if ((bid & 1) == 0) {
        int gb = bid >> 1;
        if (gb >= ngemm) return;
        gemm_att_body<FIN, FOUT, false>(X, W, asrc, adst, H, Ssrc, Sdst, n, gb);
    } else {
        int cb = bid >> 1;
        if (cb >= NCOUNT) return;
        if (cb == 0 && threadIdx.x < 32) facc[threadIdx.x] = 0.f;
        int tidg = cb * BLOCK + threadIdx.x;
        int nthr = NCOUNT * BLOCK;
        for (int base = tidg; base < E; base += 4 * nthr) {
            int idx[4], d[4], r[4];
            bool ok[4];
#pragma unroll
            for (int u = 0; u < 4; ++u) {
                idx[u] = base + u * nthr;
                ok[u] = idx[u] < E;
                d[u] = dst[ok[u] ? idx[u] : 0];
            }
#pragma unroll
            for (int u = 0; u < 4; ++u)
                if (ok[u]) r[u] = atomicAdd(&counts[(size_t)d[u] * CPAD], 1);
#pragma unroll
            for (int u = 0; u < 4; ++u)
                if (ok[u]) rank[idx[u]] = r[u];
        }
    }
}

// Core: fused softmax + gather-FMA for one node (F-lane group). Returns the
// normalized aggregation value for (node, lane) — bias NOT included.
// Uses the caller's per-group LDS stash (wldsg/ildsg, NS=K*F slots, 16-mult).
template <int F, int K>
__device__ __forceinline__ float aggr_node_core(
    const unsigned short* __restrict__ H, const float* __restrict__ Ssrc,
    const float* __restrict__ Sdst, const int* __restrict__ row_start,
    const int* __restrict__ esrc, int node, int lane,
    float* wldsg, int* ildsg) {
    constexpr int NS = K * F;
    int rs = row_start[node];
    int deg = row_start[node + 1] - rs;
    float sdi = Sdst[node];
    float selft = llrelu(Ssrc[node] + sdi);

    float wreg[K];
#pragma unroll
    for (int k = 0; k < K; ++k) {
        wldsg[k * F + lane] = 0.f;
        ildsg[k * F + lane] = node * F;
    }

    float m = selft;
#pragma unroll
    for (int k = 0; k < K; ++k) {
        int j = k * F + lane;
        if (j < deg) {
            int s = esrc[rs + j];
            float t = llrelu(Ssrc[s] + sdi);
            ildsg[j] = s * F;
            wreg[k] = t;
            m = fmaxf(m, t);
        }
    }
    for (int j = NS + lane; j < deg; j += F)
        m = fmaxf(m, llrelu(Ssrc[esrc[rs + j]] + sdi));
#pragma unroll
    for (int off = F / 2; off > 0; off >>= 1) m = fmaxf(m, __shfl_xor(m, off, F));

    float selfw = __expf(selft - m);
    float l = (lane == 0) ? selfw : 0.f;
#pragma unroll
    for (int k = 0; k < K; ++k) {
        int j = k * F + lane;
        if (j < deg) {
            float e = __expf(wreg[k] - m);
            wldsg[j] = e;
            l += e;
        }
    }
    for (int j = NS + lane; j < deg; j += F)
        l += __expf(llrelu(Ssrc[esrc[rs + j]] + sdi) - m);
#pragma unroll
    for (int off = F / 2; off > 0; off >>= 1) l += __shfl_xor(l, off, F);
    float winv = 1.f / l;

    float acc = selfw * bf2f(H[(size_t)node * F + lane]);
    int nbv = deg < NS ? deg : NS;
    for (int j0 = 0; j0 < nbv; j0 += 16) {
        float4 w0 = *(const float4*)&wldsg[j0];
        float4 w1 = *(const float4*)&wldsg[j0 + 4];
        float4 w2 = *(const float4*)&wldsg[j0 + 8];
        float4 w3 = *(const float4*)&wldsg[j0 + 12];
        int4 i0 = *(const int4*)&ildsg[j0];
        int4 i1 = *(const int4*)&ildsg[j0 + 4];
        int4 i2 = *(const int4*)&ildsg[j0 + 8];
        int4 i3 = *(const int4*)&ildsg[j0 + 12];
        int ix[16] = {i0.x, i0.y, i0.z, i0.w, i1.x, i1.y, i1.z, i1.w,
                      i2.x, i2.y, i2.z, i2.w, i3.x, i3.y, i3.z, i3.w};
        float wv[16] = {w0.x, w0.y, w0.z, w0.w, w1.x, w1.y, w1.z, w1.w,
                        w2.x, w2.y, w2.z, w2.w, w3.x, w3.y, w3.z, w3.w};
        unsigned short hv[16];
#pragma unroll
        for (int u = 0; u < 16; ++u) hv[u] = H[(size_t)(unsigned)(ix[u] + lane)];
#pragma unroll
        for (int u = 0; u < 16; ++u) acc = fmaf(wv[u], bf2f(hv[u]), acc);
    }
    for (int j = NS; j < deg; ++j) {
        int s = esrc[rs + j];
        float wj = __expf(llrelu(Ssrc[s] + sdi) - m);
        acc = fmaf(wj, bf2f(H[(size_t)s * F + lane]), acc);
    }
    return acc * winv;
}

// Layer-1 aggregation + layer-2 GEMM epilogue. 4 nodes/block (64-lane groups).
// Group holds the full 64-dim output row; stage to LDS, multiply by W2
// (64x32, LDS), emit bf16 H2 + layer-2 attention dots. B1 never materialized.
__global__ void aggr1_gemm2_kernel(const unsigned short* __restrict__ H1,
                                   const float* __restrict__ ssA, const float* __restrict__ sdA,
                                   const int* __restrict__ rowst, const int* __restrict__ esrc,
                                   const float* __restrict__ b1, const float* __restrict__ W2,
                                   const float* __restrict__ as2, const float* __restrict__ ad2,
                                   unsigned short* __restrict__ H2,
                                   float* __restrict__ ssB, float* __restrict__ sdB, int n) {
    __shared__ __align__(16) float wlds[4][128];
    __shared__ __align__(16) int ilds[4][128];
    __shared__ float Ws2[64 * 32];
    __shared__ float Xs2[4][64];
    int tid = threadIdx.x;
    for (int t = tid; t < 64 * 32 / 4; t += BLOCK) ((float4*)Ws2)[t] = ((const float4*)W2)[t];
    __syncthreads();

    int grp = tid >> 6, lane = tid & 63;
    int node = blockIdx.x * 4 + grp;
    if (node >= n) return;  // n % 4 == 0 for this problem; no barriers follow

    float acc = aggr_node_core<64, 2>(H1, ssA, sdA, rowst, esrc, node, lane,
                                      wlds[grp], ilds[grp]);
    Xs2[grp][lane] = fmaxf(acc + b1[lane], 0.f);  // relu(out1) = layer-2 input

    int c = lane & 31, half = lane >> 5;
    float part = 0.f;
#pragma unroll
    for (int k = 0; k < 32; ++k) {
        int kk = half * 32 + k;
        part = fmaf(Xs2[grp][kk], Ws2[kk * 32 + c], part);
    }
    float h2 = part + __shfl_xor(part, 32, 64);  // combine k-halves
    if (lane < 32) H2[(size_t)node * 32 + lane] = f2bf(h2);
    float vs = h2 * as2[c], vd = h2 * ad2[c];
#pragma unroll
    for (int off = 16; off > 0; off >>= 1) {
        vs += __shfl_xor(vs, off, 32);
        vd += __shfl_xor(vd, off, 32);
    }
    if (lane == 0) { ssB[node] = vs; sdB[node] = vd; }
}

// Layer-2 aggregation + layer-3 GEMM epilogue. 8 nodes/block (32-lane groups).
__global__ void aggr2_gemm3_kernel(const unsigned short* __restrict__ H2,
                                   const float* __restrict__ ssB, const float* __restrict__ sdB,
                                   const int* __restrict__ rowst, const int* __restrict__ esrc,
                                   const float* __restrict__ b2, const float* __restrict__ W3,
                                   const float* __restrict__ as3, const float* __restrict__ ad3,
                                   unsigned short* __restrict__ H3,
                                   float* __restrict__ ssC, float* __restrict__ sdC, int n) {
    __shared__ __align__(16) float wlds[8][128];
    __shared__ __align__(16) int ilds[8][128];
    __shared__ float Ws3[32 * 32];
    __shared__ float Xs3[8][32];
    int tid = threadIdx.x;
    if (tid < 256) ((float4*)Ws3)[tid] = ((const float4*)W3)[tid];
    __syncthreads();

    int grp = tid >> 5, lane = tid & 31;
    int node = blockIdx.x * 8 + grp;
    if (node >= n) return;  // n % 8 == 0; no barriers follow

    float acc = aggr_node_core<32, 4>(H2, ssB, sdB, rowst, esrc, node, lane,
                                      wlds[grp], ilds[grp]);
    Xs3[grp][lane] = fmaxf(acc + b2[lane], 0.f);

    float part = 0.f;
#pragma unroll
    for (int k = 0; k < 32; ++k) part = fmaf(Xs3[grp][k], Ws3[k * 32 + lane], part);
    H3[(size_t)node * 32 + lane] = f2bf(part);
    float vs = part * as3[lane], vd = part * ad3[lane];
#pragma unroll
    for (int off = 16; off > 0; off >>= 1) {
        vs += __shfl_xor(vs, off, 32);
        vd += __shfl_xor(vd, off, 32);
    }
    if (lane == 0) { ssC[node] = vs; sdC[node] = vd; }
}

// Layer-3 aggregation + mean. Grid-stride over nodes; per-thread partial sums,
// LDS reduce, 32 atomics/block. B3 never materialized.
__global__ void aggr3_mean_kernel(const unsigned short* __restrict__ H3,
                                  const float* __restrict__ ssC, const float* __restrict__ sdC,
                                  const int* __restrict__ rowst, const int* __restrict__ esrc,
                                  float* __restrict__ facc, int n) {
    __shared__ __align__(16) float wlds[8][128];
    __shared__ __align__(16) int ilds[8][128];
    __shared__ float msum[32];
    int tid = threadIdx.x;
    int grp = tid >> 5, lane = tid & 31;

    float psum = 0.f;
    for (int node = blockIdx.x * 8 + grp; node < n; node += gridDim.x * 8)
        psum += aggr_node_core<32, 4>(H3, ssC, sdC, rowst, esrc, node, lane,
                                      wlds[grp], ilds[grp]);

    if (tid < 32) msum[tid] = 0.f;
    __syncthreads();
    atomicAdd(&msum[lane], psum);
    __syncthreads();
    if (tid < 32) atomicAdd(&facc[tid], msum[tid]);
}

__global__ void finalize_kernel(const float* __restrict__ facc, const float* __restrict__ b,
                                const float* __restrict__ tdp, const float* __restrict__ cansup,
                                float* __restrict__ out, int n) {
    int f = threadIdx.x;
    if (f < 32) {
        float td = tdp[0] * cansup[0];
        out[f] = (facc[f] / (float)n + b[f]) * td;
    }
}

extern "C" void kernel_launch(void* const* d_in, const int* in_sizes, int n_in,
                              void* d_out, int out_size, void* d_ws, size_t ws_size,
                              hipStream_t stream) {
    const float* x      = (const float*)d_in[0];
    const int* eidx     = (const int*)d_in[1];
    const float* W1     = (const float*)d_in[2];
    const float* as1    = (const float*)d_in[3];
    const float* ad1    = (const float*)d_in[4];
    const float* b1     = (const float*)d_in[5];
    const float* W2     = (const float*)d_in[6];
    const float* as2    = (const float*)d_in[7];
    const float* ad2    = (const float*)d_in[8];
    const float* b2     = (const float*)d_in[9];
    const float* W3     = (const float*)d_in[10];
    const float* as3    = (const float*)d_in[11];
    const float* ad3    = (const float*)d_in[12];
    const float* b3     = (const float*)d_in[13];
    const float* tdp    = (const float*)d_in[14];
    const float* cansup = (const float*)d_in[15];

    const int n = in_sizes[0] / 64;   // 100000 nodes
    const int E = in_sizes[1] / 2;    // 1600000 edges
    const int* srcp = eidx;
    const int* dstp = eidx + E;

    char* ws = (char*)d_ws;
    size_t off = 0;
    auto alloc = [&](size_t bytes) -> void* {
        void* p = ws + off;
        off += (bytes + 255) & ~(size_t)255;
        return p;
    };
    unsigned short* H1 = (unsigned short*)alloc((size_t)n * 64 * sizeof(unsigned short));
    unsigned short* H2 = (unsigned short*)alloc((size_t)n * 32 * sizeof(unsigned short));
    unsigned short* H3 = (unsigned short*)alloc((size_t)n * 32 * sizeof(unsigned short));
    float* ssA    = (float*)alloc((size_t)n * sizeof(float));
    float* sdA    = (float*)alloc((size_t)n * sizeof(float));
    float* ssB    = (float*)alloc((size_t)n * sizeof(float));
    float* sdB    = (float*)alloc((size_t)n * sizeof(float));
    float* ssC    = (float*)alloc((size_t)n * sizeof(float));
    float* sdC    = (float*)alloc((size_t)n * sizeof(float));
    int*   counts = (int*)alloc((size_t)n * CPAD * sizeof(int));
    int*   rowst  = (int*)alloc((size_t)(n + 1) * sizeof(int));
    int*   bsums  = (int*)alloc(1024 * sizeof(int));
    int*   esrc   = (int*)alloc((size_t)E * sizeof(int));
    int*   rank   = (int*)alloc((size_t)E * sizeof(int));
    float* facc   = (float*)alloc(64 * sizeof(float));

    // ---- CSR build overlapped with layer-1 GEMM ----
    zero_strided_kernel<<<(n + 255) / 256, 256, 0, stream>>>(counts, n);
    const int ngemm1 = (n + 63) / 64;
    const int gmax = (ngemm1 > NCOUNT) ? ngemm1 : NCOUNT;
    gemm_att_count_kernel<64, 64><<<2 * gmax, BLOCK, 0, stream>>>(
        x, W1, as1, ad1, H1, ssA, sdA, n, ngemm1, dstp, E, counts, rank, facc);
    int nb = (n + 1023) / 1024;
    scan_phase1<<<nb, 1024, 0, stream>>>(counts, n, rowst, bsums);
    scan_phase2<<<1, 1024, 0, stream>>>(bsums, nb);
    scan_phase3<<<(n + 255) / 256, 256, 0, stream>>>(rowst, bsums, n, E);
    fill_kernel<<<1024, 256, 0, stream>>>(srcp, dstp, rank, E, rowst, esrc);

    // ---- layer 1 aggregation + layer 2 GEMM ----
    aggr1_gemm2_kernel<<<(n + 3) / 4, BLOCK, 0, stream>>>(
        H1, ssA, sdA, rowst, esrc, b1, W2, as2, ad2, H2, ssB, sdB, n);

    // ---- layer 2 aggregation + layer 3 GEMM ----
    aggr2_gemm3_kernel<<<(n + 7) / 8, BLOCK, 0, stream>>>(
        H2, ssB, sdB, rowst, esrc, b2, W3, as3, ad3, H3, ssC, sdC, n);

    // ---- layer 3 aggregation + mean ----
    aggr3_mean_kernel<<<2048, BLOCK, 0, stream>>>(H3, ssC, sdC, rowst, esrc, facc, n);
    finalize_kernel<<<1, 64, 0, stream>>>(facc, b3, tdp, cansup, (float*)d_out, n);
}

// Round 10
// 237.293 us; speedup vs baseline: 1.1614x; 1.1614x over previous
//
#include <hip/hip_runtime.h>

// 3-layer GAT (PyG GATConv) on MI355X.
// CSR build via two-level counting sort — NO global atomics (R8 showed
// returning global atomics cap at ~25G/s => 64us wall for 1.6M edges):
//   A: per-block LDS histogram over 1563 coarse buckets (64 nodes each),
//      layer-1 GEMM rides on even blocks (heterogeneous, LDS union).
//   scan: 3-pass exclusive scan of the 800k-cell (bucket x block) matrix.
//   C: re-read chunk, LDS returning-atomic cursors -> scatter (src,dst)
//      pairs into bucket-contiguous regions.
//   D: one block per bucket: LDS 64-hist + scan -> rowst + in-bucket esrc.
// Layers: gemm_att (micro-tiled LDS GEMM, bf16 H epilogue) -> gat_aggr
// (fused softmax + gather over bf16 H, LDS edge stash, 16 gathers in
// flight). aggr3 fused with the global mean (B3 never materialized).

constexpr int BLOCK = 256;
constexpr int NBLK = 512;  // hist/scatter blocks (chunked edge ownership)
constexpr int BSH = 6;     // 64 nodes per bucket
constexpr int MAXNB = 1600;  // max buckets (n <= 102400)

__device__ __forceinline__ float llrelu(float x) { return x >= 0.f ? x : 0.2f * x; }

__device__ __forceinline__ unsigned short f2bf(float f) {
    unsigned int u = __float_as_uint(f);
    u += 0x7FFFu + ((u >> 16) & 1u);  // round-to-nearest-even
    return (unsigned short)(u >> 16);
}
__device__ __forceinline__ float bf2f(unsigned short h) {
    return __uint_as_float((unsigned int)h << 16);
}

// ---------- GEMM body (H bf16 + attention dots), LDS provided by caller ----------
template <int FIN, int FOUT, bool RELU_IN>
__device__ __forceinline__ void gemm_att_body(
    const float* __restrict__ X, const float* __restrict__ W,
    const float* __restrict__ asrc, const float* __restrict__ adst,
    unsigned short* __restrict__ H, float* __restrict__ Ssrc,
    float* __restrict__ Sdst, int n, int gblk, float* Xs, float* Ws) {
    constexpr int CG = FOUT / 4;
    constexpr int NG = BLOCK / CG;
    constexpr int TN = NG * 4;
    constexpr int S = FIN + 4;

    int tid = threadIdx.x;
    int n0_blk = gblk * TN;

    for (int t = tid; t < FIN * FOUT / 4; t += BLOCK) {
        float4 v = ((const float4*)W)[t];
        *(float4*)&Ws[t * 4] = v;
    }
    constexpr int RW = FIN / 4;
    for (int t = tid; t < TN * RW; t += BLOCK) {
        int r = t / RW, c = t % RW;
        int gr = n0_blk + r;
        if (gr >= n) gr = n - 1;
        float4 v = ((const float4*)(X + (size_t)gr * FIN))[c];
        if (RELU_IN) {
            v.x = fmaxf(v.x, 0.f); v.y = fmaxf(v.y, 0.f);
            v.z = fmaxf(v.z, 0.f); v.w = fmaxf(v.w, 0.f);
        }
        *(float4*)&Xs[r * S + c * 4] = v;
    }
    __syncthreads();

    int tx = tid % CG, ty = tid / CG;
    int c0 = tx * 4, nloc = ty * 4;

    float acc[4][4];
#pragma unroll
    for (int i = 0; i < 4; ++i)
#pragma unroll
        for (int j = 0; j < 4; ++j) acc[i][j] = 0.f;

#pragma unroll 2
    for (int kc = 0; kc < FIN / 4; ++kc) {
        float4 xv[4], wv[4];
#pragma unroll
        for (int i = 0; i < 4; ++i) xv[i] = *(const float4*)&Xs[(nloc + i) * S + kc * 4];
#pragma unroll
        for (int kk = 0; kk < 4; ++kk) wv[kk] = *(const float4*)&Ws[(kc * 4 + kk) * FOUT + c0];
#pragma unroll
        for (int i = 0; i < 4; ++i) {
            float xi0 = xv[i].x, xi1 = xv[i].y, xi2 = xv[i].z, xi3 = xv[i].w;
            acc[i][0] = fmaf(xi0, wv[0].x, acc[i][0]);
            acc[i][1] = fmaf(xi0, wv[0].y, acc[i][1]);
            acc[i][2] = fmaf(xi0, wv[0].z, acc[i][2]);
            acc[i][3] = fmaf(xi0, wv[0].w, acc[i][3]);
            acc[i][0] = fmaf(xi1, wv[1].x, acc[i][0]);
            acc[i][1] = fmaf(xi1, wv[1].y, acc[i][1]);
            acc[i][2] = fmaf(xi1, wv[1].z, acc[i][2]);
            acc[i][3] = fmaf(xi1, wv[1].w, acc[i][3]);
            acc[i][0] = fmaf(xi2, wv[2].x, acc[i][0]);
            acc[i][1] = fmaf(xi2, wv[2].y, acc[i][1]);
            acc[i][2] = fmaf(xi2, wv[2].z, acc[i][2]);
            acc[i][3] = fmaf(xi2, wv[2].w, acc[i][3]);
            acc[i][0] = fmaf(xi3, wv[3].x, acc[i][0]);
            acc[i][1] = fmaf(xi3, wv[3].y, acc[i][1]);
            acc[i][2] = fmaf(xi3, wv[3].z, acc[i][2]);
            acc[i][3] = fmaf(xi3, wv[3].w, acc[i][3]);
        }
    }

    float4 as4 = *(const float4*)&asrc[c0];
    float4 ad4 = *(const float4*)&adst[c0];

#pragma unroll
    for (int i = 0; i < 4; ++i) {
        int node = n0_blk + nloc + i;
        bool ok = node < n;
        if (ok) {
            ushort4 hb;
            hb.x = f2bf(acc[i][0]); hb.y = f2bf(acc[i][1]);
            hb.z = f2bf(acc[i][2]); hb.w = f2bf(acc[i][3]);
            *(ushort4*)&H[(size_t)node * FOUT + c0] = hb;
        }
        float vs = acc[i][0] * as4.x + acc[i][1] * as4.y + acc[i][2] * as4.z + acc[i][3] * as4.w;
        float vd = acc[i][0] * ad4.x + acc[i][1] * ad4.y + acc[i][2] * ad4.z + acc[i][3] * ad4.w;
#pragma unroll
        for (int off = CG / 2; off > 0; off >>= 1) {
            vs += __shfl_xor(vs, off, CG);
            vd += __shfl_xor(vd, off, CG);
        }
        if (tx == 0 && ok) {
            Ssrc[node] = vs;
            Sdst[node] = vd;
        }
    }
}

template <int FIN, int FOUT, bool RELU_IN>
__global__ void gemm_att_kernel(const float* __restrict__ X, const float* __restrict__ W,
                                const float* __restrict__ asrc, const float* __restrict__ adst,
                                unsigned short* __restrict__ H, float* __restrict__ Ssrc,
                                float* __restrict__ Sdst, int n) {
    constexpr int CG = FOUT / 4;
    constexpr int NG = BLOCK / CG;
    constexpr int TN = NG * 4;
    constexpr int S = FIN + 4;
    __shared__ float Xs[TN * S];
    __shared__ float Ws[FIN * FOUT];
    gemm_att_body<FIN, FOUT, RELU_IN>(X, W, asrc, adst, H, Ssrc, Sdst, n, blockIdx.x, Xs, Ws);
}

// ---------- Phase A: coarse histogram (odd blocks) + layer-1 GEMM (even) ----------
__global__ void hist_gemm1_kernel(const float* __restrict__ X, const float* __restrict__ W,
                                  const float* __restrict__ asrc, const float* __restrict__ adst,
                                  unsigned short* __restrict__ H, float* __restrict__ Ssrc,
                                  float* __restrict__ Sdst, int n, int ngemm,
                                  const int* __restrict__ dst, int E, int chunk, int NB,
                                  int* __restrict__ S, float* __restrict__ facc) {
    // LDS union: gemm<64,64> needs 64*68 + 64*64 = 8448 floats; hist needs 1600 ints.
    __shared__ __align__(16) float lds[8448];
    int bid = blockIdx.x;
    if ((bid & 1) == 0) {
        int gb = bid >> 1;
        if (gb >= ngemm) return;
        gemm_att_body<64, 64, false>(X, W, asrc, adst, H, Ssrc, Sdst, n, gb, lds, lds + 64 * 68);
    } else {
        int k = bid >> 1;
        if (k >= NBLK) return;
        int* hist = (int*)lds;
        for (int i = threadIdx.x; i < NB; i += BLOCK) hist[i] = 0;
        if (k == 0 && threadIdx.x < 32) facc[threadIdx.x] = 0.f;
        __syncthreads();
        int start = k * chunk, end = min(E, start + chunk);
        for (int i = start + threadIdx.x; i < end; i += BLOCK)
            atomicAdd(&hist[dst[i] >> BSH], 1);
        __syncthreads();
        for (int b = threadIdx.x; b < NB; b += BLOCK) S[(size_t)b * NBLK + k] = hist[b];
    }
}

// ---------- 3-pass exclusive scan over S[NB*NBLK] ----------
__global__ void scan1_kernel(int* __restrict__ S, int total, int* __restrict__ bsums) {
    __shared__ int s[1024];
    int tid = threadIdx.x;
    int gid = blockIdx.x * 1024 + tid;
    int v = (gid < total) ? S[gid] : 0;
    s[tid] = v;
    for (int off = 1; off < 1024; off <<= 1) {
        __syncthreads();
        int t = (tid >= off) ? s[tid - off] : 0;
        __syncthreads();
        s[tid] += t;
    }
    __syncthreads();
    if (gid < total) S[gid] = s[tid] - v;  // exclusive within block
    if (tid == 1023) bsums[blockIdx.x] = s[tid];
}

__global__ void scan2_kernel(int* __restrict__ bsums, int nb) {
    __shared__ int s[1024];
    int tid = threadIdx.x;
    int v = (tid < nb) ? bsums[tid] : 0;
    s[tid] = v;
    for (int off = 1; off < 1024; off <<= 1) {
        __syncthreads();
        int t = (tid >= off) ? s[tid - off] : 0;
        __syncthreads();
        s[tid] += t;
    }
    __syncthreads();
    if (tid < nb) bsums[tid] = s[tid] - v;  // exclusive
}

__global__ void scan3_kernel(int* __restrict__ S, const int* __restrict__ bsums, int total) {
    int gid = blockIdx.x * blockDim.x + threadIdx.x;
    if (gid < total) S[gid] += bsums[gid >> 10];
}

// ---------- Phase C: scatter (src,dst) pairs into bucket regions ----------
__global__ void scatter_kernel(const int* __restrict__ src, const int* __restrict__ dst,
                               int E, int chunk, int NB, const int* __restrict__ S,
                               int2* __restrict__ pairs) {
    __shared__ int cursor[MAXNB];
    int k = blockIdx.x;
    for (int b = threadIdx.x; b < NB; b += BLOCK) cursor[b] = S[(size_t)b * NBLK + k];
    __syncthreads();
    int start = k * chunk, end = min(E, start + chunk);
    for (int i = start + threadIdx.x; i < end; i += BLOCK) {
        int d = dst[i], s = src[i];
        int pos = atomicAdd(&cursor[d >> BSH], 1);  // LDS returning atomic
        pairs[pos] = make_int2(s, d);
    }
}

// ---------- Phase D: per-bucket CSR (rowst + in-bucket dst-sorted esrc) ----------
__global__ void bucket_csr_kernel(const int2* __restrict__ pairs, const int* __restrict__ S,
                                  int NB, int n, int E, int* __restrict__ rowst,
                                  int* __restrict__ esrc) {
    __shared__ int cnt[64], excl[64];
    int b = blockIdx.x;
    if (b >= NB) return;
    int base = S[(size_t)b * NBLK];
    int end = (b + 1 < NB) ? S[(size_t)(b + 1) * NBLK] : E;
    int m = end - base;
    if (threadIdx.x < 64) cnt[threadIdx.x] = 0;
    __syncthreads();
    for (int i = threadIdx.x; i < m; i += BLOCK)
        atomicAdd(&cnt[pairs[base + i].y & 63], 1);
    __syncthreads();
    if (threadIdx.x == 0) {
        int run = 0;
        for (int j = 0; j < 64; ++j) { excl[j] = run; run += cnt[j]; }
    }
    __syncthreads();
    int node0 = b << BSH;
    if (threadIdx.x < 64) {
        int node = node0 + threadIdx.x;
        if (node < n) rowst[node] = base + excl[threadIdx.x];
        cnt[threadIdx.x] = excl[threadIdx.x];  // becomes the running cursor
    }
    if (b == NB - 1 && threadIdx.x == 0) rowst[n] = E;
    __syncthreads();
    for (int i = threadIdx.x; i < m; i += BLOCK) {
        int2 p = pairs[base + i];
        int pos = atomicAdd(&cnt[p.y & 63], 1);  // LDS returning atomic
        esrc[base + pos] = p.x;
    }
}

// ---------- fused softmax + gather core (proven in R6-R9) ----------
template <int F, int K>
__device__ __forceinline__ float aggr_node_core(
    const unsigned short* __restrict__ H, const float* __restrict__ Ssrc,
    const float* __restrict__ Sdst, const int* __restrict__ row_start,
    const int* __restrict__ esrc, int node, int lane,
    float* wldsg, int* ildsg) {
    constexpr int NS = K * F;
    int rs = row_start[node];
    int deg = row_start[node + 1] - rs;
    float sdi = Sdst[node];
    float selft = llrelu(Ssrc[node] + sdi);

    float wreg[K];
#pragma unroll
    for (int k = 0; k < K; ++k) {
        wldsg[k * F + lane] = 0.f;
        ildsg[k * F + lane] = node * F;
    }

    float m = selft;
#pragma unroll
    for (int k = 0; k < K; ++k) {
        int j = k * F + lane;
        if (j < deg) {
            int s = esrc[rs + j];
            float t = llrelu(Ssrc[s] + sdi);
            ildsg[j] = s * F;
            wreg[k] = t;
            m = fmaxf(m, t);
        }
    }
    for (int j = NS + lane; j < deg; j += F)
        m = fmaxf(m, llrelu(Ssrc[esrc[rs + j]] + sdi));
#pragma unroll
    for (int off = F / 2; off > 0; off >>= 1) m = fmaxf(m, __shfl_xor(m, off, F));

    float selfw = __expf(selft - m);
    float l = (lane == 0) ? selfw : 0.f;
#pragma unroll
    for (int k = 0; k < K; ++k) {
        int j = k * F + lane;
        if (j < deg) {
            float e = __expf(wreg[k] - m);
            wldsg[j] = e;
            l += e;
        }
    }
    for (int j = NS + lane; j < deg; j += F)
        l += __expf(llrelu(Ssrc[esrc[rs + j]] + sdi) - m);
#pragma unroll
    for (int off = F / 2; off > 0; off >>= 1) l += __shfl_xor(l, off, F);
    float winv = 1.f / l;

    float acc = selfw * bf2f(H[(size_t)node * F + lane]);
    int nbv = deg < NS ? deg : NS;
    for (int j0 = 0; j0 < nbv; j0 += 16) {
        float4 w0 = *(const float4*)&wldsg[j0];
        float4 w1 = *(const float4*)&wldsg[j0 + 4];
        float4 w2 = *(const float4*)&wldsg[j0 + 8];
        float4 w3 = *(const float4*)&wldsg[j0 + 12];
        int4 i0 = *(const int4*)&ildsg[j0];
        int4 i1 = *(const int4*)&ildsg[j0 + 4];
        int4 i2 = *(const int4*)&ildsg[j0 + 8];
        int4 i3 = *(const int4*)&ildsg[j0 + 12];
        int ix[16] = {i0.x, i0.y, i0.z, i0.w, i1.x, i1.y, i1.z, i1.w,
                      i2.x, i2.y, i2.z, i2.w, i3.x, i3.y, i3.z, i3.w};
        float wv[16] = {w0.x, w0.y, w0.z, w0.w, w1.x, w1.y, w1.z, w1.w,
                        w2.x, w2.y, w2.z, w2.w, w3.x, w3.y, w3.z, w3.w};
        unsigned short hv[16];
#pragma unroll
        for (int u = 0; u < 16; ++u) hv[u] = H[(size_t)(unsigned)(ix[u] + lane)];
#pragma unroll
        for (int u = 0; u < 16; ++u) acc = fmaf(wv[u], bf2f(hv[u]), acc);
    }
    for (int j = NS; j < deg; ++j) {
        int s = esrc[rs + j];
        float wj = __expf(llrelu(Ssrc[s] + sdi) - m);
        acc = fmaf(wj, bf2f(H[(size_t)s * F + lane]), acc);
    }
    return acc * winv;
}

// Standalone aggregation (layers 1, 2): OUT f32 (+bias), consumed by next gemm.
template <int F, int K, bool WITH_BIAS>
__global__ void gat_aggr_kernel(const unsigned short* __restrict__ H,
                                const float* __restrict__ Ssrc, const float* __restrict__ Sdst,
                                const int* __restrict__ rowst, const int* __restrict__ esrc,
                                const float* __restrict__ bias, float* __restrict__ OUT, int n) {
    constexpr int GPB = BLOCK / F;
    __shared__ __align__(16) float wlds[GPB][K * F];
    __shared__ __align__(16) int ilds[GPB][K * F];
    int tid = threadIdx.x;
    int grp = tid / F, lane = tid % F;
    int node = blockIdx.x * GPB + grp;
    if (node >= n) return;
    float acc = aggr_node_core<F, K>(H, Ssrc, Sdst, rowst, esrc, node, lane,
                                     wlds[grp], ilds[grp]);
    if (WITH_BIAS) acc += bias[lane];
    OUT[(size_t)node * F + lane] = acc;
}

// Layer-3 aggregation + mean. Grid-stride; B3 never materialized.
__global__ void aggr3_mean_kernel(const unsigned short* __restrict__ H3,
                                  const float* __restrict__ ssC, const float* __restrict__ sdC,
                                  const int* __restrict__ rowst, const int* __restrict__ esrc,
                                  float* __restrict__ facc, int n) {
    __shared__ __align__(16) float wlds[8][128];
    __shared__ __align__(16) int ilds[8][128];
    __shared__ float msum[32];
    int tid = threadIdx.x;
    int grp = tid >> 5, lane = tid & 31;

    float psum = 0.f;
    for (int node = blockIdx.x * 8 + grp; node < n; node += gridDim.x * 8)
        psum += aggr_node_core<32, 4>(H3, ssC, sdC, rowst, esrc, node, lane,
                                      wlds[grp], ilds[grp]);

    if (tid < 32) msum[tid] = 0.f;
    __syncthreads();
    atomicAdd(&msum[lane], psum);
    __syncthreads();
    if (tid < 32) atomicAdd(&facc[tid], msum[tid]);
}

__global__ void finalize_kernel(const float* __restrict__ facc, const float* __restrict__ b,
                                const float* __restrict__ tdp, const float* __restrict__ cansup,
                                float* __restrict__ out, int n) {
    int f = threadIdx.x;
    if (f < 32) {
        float td = tdp[0] * cansup[0];
        out[f] = (facc[f] / (float)n + b[f]) * td;
    }
}

extern "C" void kernel_launch(void* const* d_in, const int* in_sizes, int n_in,
                              void* d_out, int out_size, void* d_ws, size_t ws_size,
                              hipStream_t stream) {
    const float* x      = (const float*)d_in[0];
    const int* eidx     = (const int*)d_in[1];
    const float* W1     = (const float*)d_in[2];
    const float* as1    = (const float*)d_in[3];
    const float* ad1    = (const float*)d_in[4];
    const float* b1     = (const float*)d_in[5];
    const float* W2     = (const float*)d_in[6];
    const float* as2    = (const float*)d_in[7];
    const float* ad2    = (const float*)d_in[8];
    const float* b2     = (const float*)d_in[9];
    const float* W3     = (const float*)d_in[10];
    const float* as3    = (const float*)d_in[11];
    const float* ad3    = (const float*)d_in[12];
    const float* b3     = (const float*)d_in[13];
    const float* tdp    = (const float*)d_in[14];
    const float* cansup = (const float*)d_in[15];

    const int n = in_sizes[0] / 64;   // 100000 nodes
    const int E = in_sizes[1] / 2;    // 1600000 edges
    const int* srcp = eidx;
    const int* dstp = eidx + E;

    const int NB = (n + 63) >> BSH;           // 1563 buckets
    const int chunk = (E + NBLK - 1) / NBLK;  // edges per hist/scatter block
    const int total = NB * NBLK;              // scan matrix size

    char* ws = (char*)d_ws;
    size_t off = 0;
    auto alloc = [&](size_t bytes) -> void* {
        void* p = ws + off;
        off += (bytes + 255) & ~(size_t)255;
        return p;
    };
    unsigned short* H1 = (unsigned short*)alloc((size_t)n * 64 * sizeof(unsigned short));
    unsigned short* H2 = (unsigned short*)alloc((size_t)n * 32 * sizeof(unsigned short));
    unsigned short* H3 = (unsigned short*)alloc((size_t)n * 32 * sizeof(unsigned short));
    float* B      = (float*)alloc((size_t)n * 64 * sizeof(float));  // f32 layer output
    float* ssA    = (float*)alloc((size_t)n * sizeof(float));
    float* sdA    = (float*)alloc((size_t)n * sizeof(float));
    float* ssB    = (float*)alloc((size_t)n * sizeof(float));
    float* sdB    = (float*)alloc((size_t)n * sizeof(float));
    float* ssC    = (float*)alloc((size_t)n * sizeof(float));
    float* sdC    = (float*)alloc((size_t)n * sizeof(float));
    int*   S      = (int*)alloc((size_t)total * sizeof(int));
    int*   bsums  = (int*)alloc(1024 * sizeof(int));
    int*   rowst  = (int*)alloc((size_t)(n + 1) * sizeof(int));
    int*   esrc   = (int*)alloc((size_t)E * sizeof(int));
    int2*  pairs  = (int2*)alloc((size_t)E * sizeof(int2));
    float* facc   = (float*)alloc(64 * sizeof(float));

    // ---- CSR build (counting sort, no global atomics) + layer-1 GEMM ----
    const int ngemm1 = (n + 63) / 64;
    const int gmax = (ngemm1 > NBLK) ? ngemm1 : NBLK;
    hist_gemm1_kernel<<<2 * gmax, BLOCK, 0, stream>>>(
        x, W1, as1, ad1, H1, ssA, sdA, n, ngemm1, dstp, E, chunk, NB, S, facc);
    int nb1 = (total + 1023) / 1024;
    scan1_kernel<<<nb1, 1024, 0, stream>>>(S, total, bsums);
    scan2_kernel<<<1, 1024, 0, stream>>>(bsums, nb1);
    scan3_kernel<<<(total + 255) / 256, 256, 0, stream>>>(S, bsums, total);
    scatter_kernel<<<NBLK, BLOCK, 0, stream>>>(srcp, dstp, E, chunk, NB, S, pairs);
    bucket_csr_kernel<<<NB, BLOCK, 0, stream>>>(pairs, S, NB, n, E, rowst, esrc);

    // ---- layer 1 aggregation ----
    gat_aggr_kernel<64, 2, true><<<(n + 3) / 4, BLOCK, 0, stream>>>(
        H1, ssA, sdA, rowst, esrc, b1, B, n);

    // ---- layer 2 ----
    gemm_att_kernel<64, 32, true><<<(n + 127) / 128, BLOCK, 0, stream>>>(
        B, W2, as2, ad2, H2, ssB, sdB, n);
    gat_aggr_kernel<32, 4, true><<<(n + 7) / 8, BLOCK, 0, stream>>>(
        H2, ssB, sdB, rowst, esrc, b2, B, n);

    // ---- layer 3 ----
    gemm_att_kernel<32, 32, true><<<(n + 127) / 128, BLOCK, 0, stream>>>(
        B, W3, as3, ad3, H3, ssC, sdC, n);
    aggr3_mean_kernel<<<2048, BLOCK, 0, stream>>>(H3, ssC, sdC, rowst, esrc, facc, n);
    finalize_kernel<<<1, 64, 0, stream>>>(facc, b3, tdp, cansup, (float*)d_out, n);
}

// Round 11
// 229.247 us; speedup vs baseline: 1.2022x; 1.0351x over previous
//
#include <hip/hip_runtime.h>

// 3-layer GAT (PyG GATConv) on MI355X.
// CSR build via two-level counting sort — NO global atomics:
//   A: per-block LDS histogram over coarse buckets (64 nodes each),
//      layer-1 GEMM rides on even blocks (heterogeneous, LDS union).
//   scan: 3-pass exclusive scan of the (bucket x block) matrix.
//   C: re-read chunk, LDS returning-atomic cursors -> scatter (src,dst).
//   D: one block per bucket: LDS 64-hist + scan -> rowst + esrc.
// Layers: gemm_att (micro-tiled LDS GEMM, bf16 H epilogue) -> gat_aggr
// (fused softmax + gather over bf16 H, LDS edge stash, 16 gathers in
// flight, ONE node per group — grid-stride serialization costs 2x, R10).
// Mean as a separate cheap kernel (R10 lesson: fusing it into a
// grid-stride aggr loses 30us of latency hiding to save 4us of traffic).

constexpr int BLOCK = 256;
constexpr int NBLK = 512;    // hist/scatter blocks (chunked edge ownership)
constexpr int BSH = 6;       // 64 nodes per bucket
constexpr int MAXNB = 1600;  // max buckets (n <= 102400)

__device__ __forceinline__ float llrelu(float x) { return x >= 0.f ? x : 0.2f * x; }

__device__ __forceinline__ unsigned short f2bf(float f) {
    unsigned int u = __float_as_uint(f);
    u += 0x7FFFu + ((u >> 16) & 1u);  // round-to-nearest-even
    return (unsigned short)(u >> 16);
}
__device__ __forceinline__ float bf2f(unsigned short h) {
    return __uint_as_float((unsigned int)h << 16);
}

// ---------- GEMM body (H bf16 + attention dots), LDS provided by caller ----------
template <int FIN, int FOUT, bool RELU_IN>
__device__ __forceinline__ void gemm_att_body(
    const float* __restrict__ X, const float* __restrict__ W,
    const float* __restrict__ asrc, const float* __restrict__ adst,
    unsigned short* __restrict__ H, float* __restrict__ Ssrc,
    float* __restrict__ Sdst, int n, int gblk, float* Xs, float* Ws) {
    constexpr int CG = FOUT / 4;
    constexpr int NG = BLOCK / CG;
    constexpr int TN = NG * 4;
    constexpr int S = FIN + 4;

    int tid = threadIdx.x;
    int n0_blk = gblk * TN;

    for (int t = tid; t < FIN * FOUT / 4; t += BLOCK) {
        float4 v = ((const float4*)W)[t];
        *(float4*)&Ws[t * 4] = v;
    }
    constexpr int RW = FIN / 4;
    for (int t = tid; t < TN * RW; t += BLOCK) {
        int r = t / RW, c = t % RW;
        int gr = n0_blk + r;
        if (gr >= n) gr = n - 1;
        float4 v = ((const float4*)(X + (size_t)gr * FIN))[c];
        if (RELU_IN) {
            v.x = fmaxf(v.x, 0.f); v.y = fmaxf(v.y, 0.f);
            v.z = fmaxf(v.z, 0.f); v.w = fmaxf(v.w, 0.f);
        }
        *(float4*)&Xs[r * S + c * 4] = v;
    }
    __syncthreads();

    int tx = tid % CG, ty = tid / CG;
    int c0 = tx * 4, nloc = ty * 4;

    float acc[4][4];
#pragma unroll
    for (int i = 0; i < 4; ++i)
#pragma unroll
        for (int j = 0; j < 4; ++j) acc[i][j] = 0.f;

#pragma unroll 2
    for (int kc = 0; kc < FIN / 4; ++kc) {
        float4 xv[4], wv[4];
#pragma unroll
        for (int i = 0; i < 4; ++i) xv[i] = *(const float4*)&Xs[(nloc + i) * S + kc * 4];
#pragma unroll
        for (int kk = 0; kk < 4; ++kk) wv[kk] = *(const float4*)&Ws[(kc * 4 + kk) * FOUT + c0];
#pragma unroll
        for (int i = 0; i < 4; ++i) {
            float xi0 = xv[i].x, xi1 = xv[i].y, xi2 = xv[i].z, xi3 = xv[i].w;
            acc[i][0] = fmaf(xi0, wv[0].x, acc[i][0]);
            acc[i][1] = fmaf(xi0, wv[0].y, acc[i][1]);
            acc[i][2] = fmaf(xi0, wv[0].z, acc[i][2]);
            acc[i][3] = fmaf(xi0, wv[0].w, acc[i][3]);
            acc[i][0] = fmaf(xi1, wv[1].x, acc[i][0]);
            acc[i][1] = fmaf(xi1, wv[1].y, acc[i][1]);
            acc[i][2] = fmaf(xi1, wv[1].z, acc[i][2]);
            acc[i][3] = fmaf(xi1, wv[1].w, acc[i][3]);
            acc[i][0] = fmaf(xi2, wv[2].x, acc[i][0]);
            acc[i][1] = fmaf(xi2, wv[2].y, acc[i][1]);
            acc[i][2] = fmaf(xi2, wv[2].z, acc[i][2]);
            acc[i][3] = fmaf(xi2, wv[2].w, acc[i][3]);
            acc[i][0] = fmaf(xi3, wv[3].x, acc[i][0]);
            acc[i][1] = fmaf(xi3, wv[3].y, acc[i][1]);
            acc[i][2] = fmaf(xi3, wv[3].z, acc[i][2]);
            acc[i][3] = fmaf(xi3, wv[3].w, acc[i][3]);
        }
    }

    float4 as4 = *(const float4*)&asrc[c0];
    float4 ad4 = *(const float4*)&adst[c0];

#pragma unroll
    for (int i = 0; i < 4; ++i) {
        int node = n0_blk + nloc + i;
        bool ok = node < n;
        if (ok) {
            ushort4 hb;
            hb.x = f2bf(acc[i][0]); hb.y = f2bf(acc[i][1]);
            hb.z = f2bf(acc[i][2]); hb.w = f2bf(acc[i][3]);
            *(ushort4*)&H[(size_t)node * FOUT + c0] = hb;
        }
        float vs = acc[i][0] * as4.x + acc[i][1] * as4.y + acc[i][2] * as4.z + acc[i][3] * as4.w;
        float vd = acc[i][0] * ad4.x + acc[i][1] * ad4.y + acc[i][2] * ad4.z + acc[i][3] * ad4.w;
#pragma unroll
        for (int off = CG / 2; off > 0; off >>= 1) {
            vs += __shfl_xor(vs, off, CG);
            vd += __shfl_xor(vd, off, CG);
        }
        if (tx == 0 && ok) {
            Ssrc[node] = vs;
            Sdst[node] = vd;
        }
    }
}

template <int FIN, int FOUT, bool RELU_IN>
__global__ void gemm_att_kernel(const float* __restrict__ X, const float* __restrict__ W,
                                const float* __restrict__ asrc, const float* __restrict__ adst,
                                unsigned short* __restrict__ H, float* __restrict__ Ssrc,
                                float* __restrict__ Sdst, int n) {
    constexpr int CG = FOUT / 4;
    constexpr int NG = BLOCK / CG;
    constexpr int TN = NG * 4;
    constexpr int S = FIN + 4;
    __shared__ float Xs[TN * S];
    __shared__ float Ws[FIN * FOUT];
    gemm_att_body<FIN, FOUT, RELU_IN>(X, W, asrc, adst, H, Ssrc, Sdst, n, blockIdx.x, Xs, Ws);
}

// ---------- Phase A: coarse histogram (odd blocks) + layer-1 GEMM (even) ----------
__global__ void hist_gemm1_kernel(const float* __restrict__ X, const float* __restrict__ W,
                                  const float* __restrict__ asrc, const float* __restrict__ adst,
                                  unsigned short* __restrict__ H, float* __restrict__ Ssrc,
                                  float* __restrict__ Sdst, int n, int ngemm,
                                  const int* __restrict__ dst, int E, int chunk, int NB,
                                  int* __restrict__ S, float* __restrict__ facc) {
    // LDS union: gemm<64,64> needs 64*68 + 64*64 = 8448 floats; hist needs 1600 ints.
    __shared__ __align__(16) float lds[8448];
    int bid = blockIdx.x;
    if ((bid & 1) == 0) {
        int gb = bid >> 1;
        if (gb >= ngemm) return;
        gemm_att_body<64, 64, false>(X, W, asrc, adst, H, Ssrc, Sdst, n, gb, lds, lds + 64 * 68);
    } else {
        int k = bid >> 1;
        if (k >= NBLK) return;
        int* hist = (int*)lds;
        for (int i = threadIdx.x; i < NB; i += BLOCK) hist[i] = 0;
        if (k == 0 && threadIdx.x < 32) facc[threadIdx.x] = 0.f;
        __syncthreads();
        int start = k * chunk, end = min(E, start + chunk);
        for (int i = start + threadIdx.x; i < end; i += BLOCK)
            atomicAdd(&hist[dst[i] >> BSH], 1);
        __syncthreads();
        for (int b = threadIdx.x; b < NB; b += BLOCK) S[(size_t)b * NBLK + k] = hist[b];
    }
}

// ---------- 3-pass exclusive scan over S[NB*NBLK] ----------
__global__ void scan1_kernel(int* __restrict__ S, int total, int* __restrict__ bsums) {
    __shared__ int s[1024];
    int tid = threadIdx.x;
    int gid = blockIdx.x * 1024 + tid;
    int v = (gid < total) ? S[gid] : 0;
    s[tid] = v;
    for (int off = 1; off < 1024; off <<= 1) {
        __syncthreads();
        int t = (tid >= off) ? s[tid - off] : 0;
        __syncthreads();
        s[tid] += t;
    }
    __syncthreads();
    if (gid < total) S[gid] = s[tid] - v;  // exclusive within block
    if (tid == 1023) bsums[blockIdx.x] = s[tid];
}

__global__ void scan2_kernel(int* __restrict__ bsums, int nb) {
    __shared__ int s[1024];
    int tid = threadIdx.x;
    int v = (tid < nb) ? bsums[tid] : 0;
    s[tid] = v;
    for (int off = 1; off < 1024; off <<= 1) {
        __syncthreads();
        int t = (tid >= off) ? s[tid - off] : 0;
        __syncthreads();
        s[tid] += t;
    }
    __syncthreads();
    if (tid < nb) bsums[tid] = s[tid] - v;  // exclusive
}

__global__ void scan3_kernel(int* __restrict__ S, const int* __restrict__ bsums, int total) {
    int gid = blockIdx.x * blockDim.x + threadIdx.x;
    if (gid < total) S[gid] += bsums[gid >> 10];
}

// ---------- Phase C: scatter (src,dst) pairs into bucket regions ----------
__global__ void scatter_kernel(const int* __restrict__ src, const int* __restrict__ dst,
                               int E, int chunk, int NB, const int* __restrict__ S,
                               int2* __restrict__ pairs) {
    __shared__ int cursor[MAXNB];
    int k = blockIdx.x;
    for (int b = threadIdx.x; b < NB; b += BLOCK) cursor[b] = S[(size_t)b * NBLK + k];
    __syncthreads();
    int start = k * chunk, end = min(E, start + chunk);
    for (int i = start + threadIdx.x; i < end; i += BLOCK) {
        int d = dst[i], s = src[i];
        int pos = atomicAdd(&cursor[d >> BSH], 1);  // LDS returning atomic
        pairs[pos] = make_int2(s, d);
    }
}

// ---------- Phase D: per-bucket CSR (rowst + in-bucket dst-sorted esrc) ----------
__global__ void bucket_csr_kernel(const int2* __restrict__ pairs, const int* __restrict__ S,
                                  int NB, int n, int E, int* __restrict__ rowst,
                                  int* __restrict__ esrc) {
    __shared__ int cnt[64], excl[64];
    int b = blockIdx.x;
    if (b >= NB) return;
    int base = S[(size_t)b * NBLK];
    int end = (b + 1 < NB) ? S[(size_t)(b + 1) * NBLK] : E;
    int m = end - base;
    if (threadIdx.x < 64) cnt[threadIdx.x] = 0;
    __syncthreads();
    for (int i = threadIdx.x; i < m; i += BLOCK)
        atomicAdd(&cnt[pairs[base + i].y & 63], 1);
    __syncthreads();
    if (threadIdx.x == 0) {
        int run = 0;
        for (int j = 0; j < 64; ++j) { excl[j] = run; run += cnt[j]; }
    }
    __syncthreads();
    int node0 = b << BSH;
    if (threadIdx.x < 64) {
        int node = node0 + threadIdx.x;
        if (node < n) rowst[node] = base + excl[threadIdx.x];
        cnt[threadIdx.x] = excl[threadIdx.x];  // becomes the running cursor
    }
    if (b == NB - 1 && threadIdx.x == 0) rowst[n] = E;
    __syncthreads();
    for (int i = threadIdx.x; i < m; i += BLOCK) {
        int2 p = pairs[base + i];
        int pos = atomicAdd(&cnt[p.y & 63], 1);  // LDS returning atomic
        esrc[base + pos] = p.x;
    }
}

// ---------- fused softmax + gather core ----------
template <int F, int K>
__device__ __forceinline__ float aggr_node_core(
    const unsigned short* __restrict__ H, const float* __restrict__ Ssrc,
    const float* __restrict__ Sdst, const int* __restrict__ row_start,
    const int* __restrict__ esrc, int node, int lane,
    float* wldsg, int* ildsg) {
    constexpr int NS = K * F;
    int rs = row_start[node];
    int deg = row_start[node + 1] - rs;
    float sdi = Sdst[node];
    float selft = llrelu(Ssrc[node] + sdi);

    float wreg[K];
#pragma unroll
    for (int k = 0; k < K; ++k) {
        wldsg[k * F + lane] = 0.f;
        ildsg[k * F + lane] = node * F;
    }

    float m = selft;
#pragma unroll
    for (int k = 0; k < K; ++k) {
        int j = k * F + lane;
        if (j < deg) {
            int s = esrc[rs + j];
            float t = llrelu(Ssrc[s] + sdi);
            ildsg[j] = s * F;
            wreg[k] = t;
            m = fmaxf(m, t);
        }
    }
    for (int j = NS + lane; j < deg; j += F)
        m = fmaxf(m, llrelu(Ssrc[esrc[rs + j]] + sdi));
#pragma unroll
    for (int off = F / 2; off > 0; off >>= 1) m = fmaxf(m, __shfl_xor(m, off, F));

    float selfw = __expf(selft - m);
    float l = (lane == 0) ? selfw : 0.f;
#pragma unroll
    for (int k = 0; k < K; ++k) {
        int j = k * F + lane;
        if (j < deg) {
            float e = __expf(wreg[k] - m);
            wldsg[j] = e;
            l += e;
        }
    }
    for (int j = NS + lane; j < deg; j += F)
        l += __expf(llrelu(Ssrc[esrc[rs + j]] + sdi) - m);
#pragma unroll
    for (int off = F / 2; off > 0; off >>= 1) l += __shfl_xor(l, off, F);
    float winv = 1.f / l;

    float acc = selfw * bf2f(H[(size_t)node * F + lane]);
    int nbv = deg < NS ? deg : NS;
    for (int j0 = 0; j0 < nbv; j0 += 16) {
        float4 w0 = *(const float4*)&wldsg[j0];
        float4 w1 = *(const float4*)&wldsg[j0 + 4];
        float4 w2 = *(const float4*)&wldsg[j0 + 8];
        float4 w3 = *(const float4*)&wldsg[j0 + 12];
        int4 i0 = *(const int4*)&ildsg[j0];
        int4 i1 = *(const int4*)&ildsg[j0 + 4];
        int4 i2 = *(const int4*)&ildsg[j0 + 8];
        int4 i3 = *(const int4*)&ildsg[j0 + 12];
        int ix[16] = {i0.x, i0.y, i0.z, i0.w, i1.x, i1.y, i1.z, i1.w,
                      i2.x, i2.y, i2.z, i2.w, i3.x, i3.y, i3.z, i3.w};
        float wv[16] = {w0.x, w0.y, w0.z, w0.w, w1.x, w1.y, w1.z, w1.w,
                        w2.x, w2.y, w2.z, w2.w, w3.x, w3.y, w3.z, w3.w};
        unsigned short hv[16];
#pragma unroll
        for (int u = 0; u < 16; ++u) hv[u] = H[(size_t)(unsigned)(ix[u] + lane)];
#pragma unroll
        for (int u = 0; u < 16; ++u) acc = fmaf(wv[u], bf2f(hv[u]), acc);
    }
    for (int j = NS; j < deg; ++j) {
        int s = esrc[rs + j];
        float wj = __expf(llrelu(Ssrc[s] + sdi) - m);
        acc = fmaf(wj, bf2f(H[(size_t)s * F + lane]), acc);
    }
    return acc * winv;
}

// Standalone aggregation: one node per group, OUT f32 (+bias optional).
template <int F, int K, bool WITH_BIAS>
__global__ void gat_aggr_kernel(const unsigned short* __restrict__ H,
                                const float* __restrict__ Ssrc, const float* __restrict__ Sdst,
                                const int* __restrict__ rowst, const int* __restrict__ esrc,
                                const float* __restrict__ bias, float* __restrict__ OUT, int n) {
    constexpr int GPB = BLOCK / F;
    __shared__ __align__(16) float wlds[GPB][K * F];
    __shared__ __align__(16) int ilds[GPB][K * F];
    int tid = threadIdx.x;
    int grp = tid / F, lane = tid % F;
    int node = blockIdx.x * GPB + grp;
    if (node >= n) return;
    float acc = aggr_node_core<F, K>(H, Ssrc, Sdst, rowst, esrc, node, lane,
                                     wlds[grp], ilds[grp]);
    if (WITH_BIAS) acc += bias[lane];
    OUT[(size_t)node * F + lane] = acc;
}

// Sum OUT3 over nodes into facc[32].
__global__ void mean_kernel(const float* __restrict__ B, float* __restrict__ facc, int n) {
    __shared__ float s[32];
    int lane = threadIdx.x & 31, row = threadIdx.x >> 5;
    float a = 0.f;
    for (int node = blockIdx.x * 8 + row; node < n; node += gridDim.x * 8)
        a += B[(size_t)node * 32 + lane];
    if (threadIdx.x < 32) s[threadIdx.x] = 0.f;
    __syncthreads();
    atomicAdd(&s[lane], a);
    __syncthreads();
    if (threadIdx.x < 32) atomicAdd(&facc[threadIdx.x], s[threadIdx.x]);
}

__global__ void finalize_kernel(const float* __restrict__ facc, const float* __restrict__ b,
                                const float* __restrict__ tdp, const float* __restrict__ cansup,
                                float* __restrict__ out, int n) {
    int f = threadIdx.x;
    if (f < 32) {
        float td = tdp[0] * cansup[0];
        out[f] = (facc[f] / (float)n + b[f]) * td;
    }
}

extern "C" void kernel_launch(void* const* d_in, const int* in_sizes, int n_in,
                              void* d_out, int out_size, void* d_ws, size_t ws_size,
                              hipStream_t stream) {
    const float* x      = (const float*)d_in[0];
    const int* eidx     = (const int*)d_in[1];
    const float* W1     = (const float*)d_in[2];
    const float* as1    = (const float*)d_in[3];
    const float* ad1    = (const float*)d_in[4];
    const float* b1     = (const float*)d_in[5];
    const float* W2     = (const float*)d_in[6];
    const float* as2    = (const float*)d_in[7];
    const float* ad2    = (const float*)d_in[8];
    const float* b2     = (const float*)d_in[9];
    const float* W3     = (const float*)d_in[10];
    const float* as3    = (const float*)d_in[11];
    const float* ad3    = (const float*)d_in[12];
    const float* b3     = (const float*)d_in[13];
    const float* tdp    = (const float*)d_in[14];
    const float* cansup = (const float*)d_in[15];

    const int n = in_sizes[0] / 64;   // 100000 nodes
    const int E = in_sizes[1] / 2;    // 1600000 edges
    const int* srcp = eidx;
    const int* dstp = eidx + E;

    const int NB = (n + 63) >> BSH;           // 1563 buckets
    const int chunk = (E + NBLK - 1) / NBLK;  // edges per hist/scatter block
    const int total = NB * NBLK;              // scan matrix size

    char* ws = (char*)d_ws;
    size_t off = 0;
    auto alloc = [&](size_t bytes) -> void* {
        void* p = ws + off;
        off += (bytes + 255) & ~(size_t)255;
        return p;
    };
    unsigned short* H1 = (unsigned short*)alloc((size_t)n * 64 * sizeof(unsigned short));
    unsigned short* H2 = (unsigned short*)alloc((size_t)n * 32 * sizeof(unsigned short));
    unsigned short* H3 = (unsigned short*)alloc((size_t)n * 32 * sizeof(unsigned short));
    float* B      = (float*)alloc((size_t)n * 64 * sizeof(float));  // f32 layer output
    float* ssA    = (float*)alloc((size_t)n * sizeof(float));
    float* sdA    = (float*)alloc((size_t)n * sizeof(float));
    float* ssB    = (float*)alloc((size_t)n * sizeof(float));
    float* sdB    = (float*)alloc((size_t)n * sizeof(float));
    float* ssC    = (float*)alloc((size_t)n * sizeof(float));
    float* sdC    = (float*)alloc((size_t)n * sizeof(float));
    int*   S      = (int*)alloc((size_t)total * sizeof(int));
    int*   bsums  = (int*)alloc(1024 * sizeof(int));
    int*   rowst  = (int*)alloc((size_t)(n + 1) * sizeof(int));
    int*   esrc   = (int*)alloc((size_t)E * sizeof(int));
    int2*  pairs  = (int2*)alloc((size_t)E * sizeof(int2));
    float* facc   = (float*)alloc(64 * sizeof(float));

    // ---- CSR build (counting sort, no global atomics) + layer-1 GEMM ----
    const int ngemm1 = (n + 63) / 64;
    const int gmax = (ngemm1 > NBLK) ? ngemm1 : NBLK;
    hist_gemm1_kernel<<<2 * gmax, BLOCK, 0, stream>>>(
        x, W1, as1, ad1, H1, ssA, sdA, n, ngemm1, dstp, E, chunk, NB, S, facc);
    int nb1 = (total + 1023) / 1024;
    scan1_kernel<<<nb1, 1024, 0, stream>>>(S, total, bsums);
    scan2_kernel<<<1, 1024, 0, stream>>>(bsums, nb1);
    scan3_kernel<<<(total + 255) / 256, 256, 0, stream>>>(S, bsums, total);
    scatter_kernel<<<NBLK, BLOCK, 0, stream>>>(srcp, dstp, E, chunk, NB, S, pairs);
    bucket_csr_kernel<<<NB, BLOCK, 0, stream>>>(pairs, S, NB, n, E, rowst, esrc);

    // ---- layer 1 aggregation ----
    gat_aggr_kernel<64, 2, true><<<(n + 3) / 4, BLOCK, 0, stream>>>(
        H1, ssA, sdA, rowst, esrc, b1, B, n);

    // ---- layer 2 ----
    gemm_att_kernel<64, 32, true><<<(n + 127) / 128, BLOCK, 0, stream>>>(
        B, W2, as2, ad2, H2, ssB, sdB, n);
    gat_aggr_kernel<32, 4, true><<<(n + 7) / 8, BLOCK, 0, stream>>>(
        H2, ssB, sdB, rowst, esrc, b2, B, n);

    // ---- layer 3 ----
    gemm_att_kernel<32, 32, true><<<(n + 127) / 128, BLOCK, 0, stream>>>(
        B, W3, as3, ad3, H3, ssC, sdC, n);
    gat_aggr_kernel<32, 4, false><<<(n + 7) / 8, BLOCK, 0, stream>>>(
        H3, ssC, sdC, rowst, esrc, nullptr, B, n);
    mean_kernel<<<1024, 256, 0, stream>>>(B, facc, n);
    finalize_kernel<<<1, 64, 0, stream>>>(facc, b3, tdp, cansup, (float*)d_out, n);
}